// Round 5
// baseline (1004.565 us; speedup 1.0000x reference)
//
#include <hip/hip_runtime.h>

#define NB 64       // batch
#define ND 512      // input dim
#define NM 1024     // memory slots
#define NR 4        // read heads
#define EPSF 1e-6f

// ---- workspace float offsets ----
static const size_t O_WV    = 0;         // B*64
static const size_t O_EV    = 4096;      // B*64
static const size_t O_FG    = 8192;      // B*4
static const size_t O_AG    = 8448;      // B
static const size_t O_WG    = 8512;      // B
static const size_t O_RMRAW = 8576;      // B*12 raw
static const size_t O_RM    = 9344;      // B*12 softmaxed
static const size_t O_WK    = 10112;     // B*64
static const size_t O_WSTR  = 14208;     // B
static const size_t O_RK    = 14272;     // B*256
static const size_t O_RSTR  = 30656;     // B*4
static const size_t O_USAGE = 30912;     // B*M
static const size_t O_WAW   = 96448;     // B*M
static const size_t O_WWGT  = 161984;    // B*M
static const size_t O_PREC  = 227520;    // B*M
static const size_t O_MN    = 293056;    // B*M
static const size_t O_WSIM  = 358592;    // B*M
static const size_t O_RSIM  = 424128;    // B*R*M
static const size_t O_FWD   = 686272;    // B*R*M
static const size_t O_BWD   = 948416;    // B*R*M
static const size_t O_RWTS  = 1210560;   // B*R*M

// ---- output element offsets (FLOAT32 elements) ----
static const size_t OO_RWORDS = 0;          // B*R*W   = 16384
static const size_t OO_MEM    = 16384;      // B*M*W   = 4194304
static const size_t OO_RW     = 4210688;    // B*R*M   = 262144
static const size_t OO_WWGT   = 4472832;    // B*1*M   = 65536
static const size_t OO_LINK   = 4538368;    // B*1*M*M = 67108864
static const size_t OO_PREC   = 71647232;   // B*1*M   = 65536
static const size_t OO_USAGE  = 71712768;   // B*M     = 65536

__device__ __forceinline__ float sigm(float x) { return 1.f / (1.f + expf(-x)); }
__device__ __forceinline__ float softplus_(float x) { return fmaxf(x, 0.f) + log1pf(expf(-fabsf(x))); }

// ================= K1: controller linears, one thread per (b, col) =================
__global__ void k_controller(
    const float* __restrict__ x,
    const float* __restrict__ wv_w, const float* __restrict__ wv_b,
    const float* __restrict__ ev_w, const float* __restrict__ ev_b,
    const float* __restrict__ fg_w, const float* __restrict__ fg_b,
    const float* __restrict__ ag_w, const float* __restrict__ ag_b,
    const float* __restrict__ wg_w, const float* __restrict__ wg_b,
    const float* __restrict__ rm_w, const float* __restrict__ rm_b,
    const float* __restrict__ ws_w, const float* __restrict__ ws_b,
    const float* __restrict__ rs_w, const float* __restrict__ rs_b,
    const float* __restrict__ wk_w, const float* __restrict__ wk_b,
    const float* __restrict__ rk_w, const float* __restrict__ rk_b,
    float* __restrict__ wsb)
{
    int b = blockIdx.x;
    int c = threadIdx.x;
    if (c >= 471) return;
    const float* wp; const float* bp; int O; int cl; int act; size_t dsto;
    if (c < 64)       { wp = wv_w; bp = wv_b; O = 64;  cl = c;       act = 0; dsto = O_WV + b * 64 + cl; }
    else if (c < 128) { wp = ev_w; bp = ev_b; O = 64;  cl = c - 64;  act = 1; dsto = O_EV + b * 64 + cl; }
    else if (c < 132) { wp = fg_w; bp = fg_b; O = 4;   cl = c - 128; act = 1; dsto = O_FG + b * 4 + cl; }
    else if (c < 133) { wp = ag_w; bp = ag_b; O = 1;   cl = 0;       act = 1; dsto = O_AG + b; }
    else if (c < 134) { wp = wg_w; bp = wg_b; O = 1;   cl = 0;       act = 1; dsto = O_WG + b; }
    else if (c < 146) { wp = rm_w; bp = rm_b; O = 12;  cl = c - 134; act = 0; dsto = O_RMRAW + b * 12 + cl; }
    else if (c < 147) { wp = ws_w; bp = ws_b; O = 1;   cl = 0;       act = 2; dsto = O_WSTR + b; }
    else if (c < 151) { wp = rs_w; bp = rs_b; O = 4;   cl = c - 147; act = 2; dsto = O_RSTR + b * 4 + cl; }
    else if (c < 215) { wp = wk_w; bp = wk_b; O = 64;  cl = c - 151; act = 0; dsto = O_WK + b * 64 + cl; }
    else              { wp = rk_w; bp = rk_b; O = 256; cl = c - 215; act = 0; dsto = O_RK + b * 256 + cl; }
    float acc = bp[cl];
    const float* xb = x + b * ND;
    for (int d = 0; d < ND; ++d) acc += xb[d] * wp[d * O + cl];
    if (act == 1) acc = sigm(acc);
    else if (act == 2) acc = softplus_(acc);
    wsb[dsto] = acc;
}

// ================= K1b: read-mode softmax =================
__global__ void k_rmsm(float* __restrict__ wsb)
{
    int i = blockIdx.x * 64 + threadIdx.x;
    if (i >= NB * NR) return;
    int b = i >> 2, r = i & 3;
    const float* raw = wsb + O_RMRAW + b * 12 + r * 3;
    float a0 = raw[0], a1 = raw[1], a2 = raw[2];
    float mx = fmaxf(a0, fmaxf(a1, a2));
    float e0 = expf(a0 - mx), e1 = expf(a1 - mx), e2 = expf(a2 - mx);
    float s = e0 + e1 + e2;
    float* dst = wsb + O_RM + b * 12 + r * 3;
    dst[0] = e0 / s; dst[1] = e1 / s; dst[2] = e2 / s;
}

// ================= K2: usage =================
__global__ void k_usage(
    const float* __restrict__ pu, const float* __restrict__ prw,
    const float* __restrict__ pww, float* __restrict__ wsb, float* __restrict__ out)
{
    int idx = blockIdx.x * 256 + threadIdx.x;
    int b = idx >> 10, m = idx & 1023;
    float u0 = pu[idx];
    float uaw = u0 + (1.f - u0) * pww[idx];
    float phi = 1.f;
#pragma unroll
    for (int r = 0; r < NR; r++)
        phi *= (1.f - wsb[O_FG + b * 4 + r] * prw[(b * 4 + r) * NM + m]);
    float u = uaw * phi;
    wsb[O_USAGE + idx] = u;
    out[OO_USAGE + idx] = u;
}

// ================= K3: allocation (odd-even sort + serial scan) =================
__global__ __launch_bounds__(1024) void k_alloc(float* __restrict__ wsb)
{
    __shared__ float sv[1024];
    __shared__ int   si[1024];
    __shared__ float sa[1024];
    int b = blockIdx.x, t = threadIdx.x;
    sv[t] = EPSF + (1.0f - EPSF) * wsb[O_USAGE + b * NM + t];
    si[t] = t;
    __syncthreads();
    for (int ph = 0; ph < 1024; ++ph) {
        int i = 2 * t + (ph & 1);
        if (i + 1 < 1024) {
            float a = sv[i], c = sv[i + 1];
            int ia = si[i], ic = si[i + 1];
            if (a > c || (a == c && ia > ic)) {
                sv[i] = c; sv[i + 1] = a; si[i] = ic; si[i + 1] = ia;
            }
        }
        __syncthreads();
    }
    if (t == 0) {
        float cum = 1.f;
        for (int k = 0; k < 1024; ++k) {
            sa[k] = (1.f - sv[k]) * cum;
            cum *= sv[k];
        }
    }
    __syncthreads();
    wsb[O_WAW + b * NM + si[t]] = sa[t];
}

// ================= K4a: write cosine sims =================
__global__ void k_wsim(const float* __restrict__ pm, float* __restrict__ wsb)
{
    int idx = blockIdx.x * 256 + threadIdx.x;
    int b = idx >> 10;
    const float* wk = wsb + O_WK + b * 64;
    const float* row = pm + (size_t)idx * 64;
    float kn2 = 0.f, dot = 0.f, mn2 = 0.f;
    for (int w = 0; w < 64; w++) {
        float kv = wk[w], pv = row[w];
        kn2 += kv * kv; dot += kv * pv; mn2 += pv * pv;
    }
    float sim = dot / (sqrtf(kn2 + EPSF) * sqrtf(mn2 + EPSF));
    wsb[O_WSIM + idx] = sim * wsb[O_WSTR + b];
}

// ================= K4b: write softmax + write_weights + precedence =================
__global__ void k_wfin(const float* __restrict__ pp, float* __restrict__ wsb, float* __restrict__ out)
{
    int b = threadIdx.x;
    if (b >= NB) return;
    const float* sim = wsb + O_WSIM + b * NM;
    float mx = -1e30f;
    for (int m = 0; m < NM; m++) mx = fmaxf(mx, sim[m]);
    float se = 0.f;
    for (int m = 0; m < NM; m++) se += expf(sim[m] - mx);
    float inv = 1.f / se;
    float ag = wsb[O_AG + b], wg = wsb[O_WG + b];
    float wwsum = 0.f;
    for (int m = 0; m < NM; m++) {
        float wcw = expf(sim[m] - mx) * inv;
        float waw = wsb[O_WAW + b * NM + m];
        float ww = wg * (ag * waw + (1.f - ag) * wcw);
        wwsum += ww;
        wsb[O_WWGT + b * NM + m] = ww;
        out[OO_WWGT + b * NM + m] = ww;
    }
    for (int m = 0; m < NM; m++) {
        float pr = (1.f - wwsum) * pp[b * NM + m] + wsb[O_WWGT + b * NM + m];
        wsb[O_PREC + b * NM + m] = pr;
        out[OO_PREC + b * NM + m] = pr;
    }
}

// ================= K5: memory update + norms =================
__global__ void k_mem(const float* __restrict__ pm, float* __restrict__ wsb, float* __restrict__ out)
{
    int gid = blockIdx.x * 256 + threadIdx.x;
    int b = gid >> 10;
    float w_ = wsb[O_WWGT + gid];
    const float* evp = wsb + O_EV + b * 64;
    const float* wvp = wsb + O_WV + b * 64;
    const float* pmr = pm + (size_t)gid * 64;
    float* outr = out + OO_MEM + (size_t)gid * 64;
    float s = 0.f;
    for (int w = 0; w < 64; w++) {
        float val = pmr[w] * (1.f - w_ * evp[w]) + w_ * wvp[w];
        outr[w] = val;
        s += val * val;
    }
    wsb[O_MN + gid] = sqrtf(s + EPSF);
}

// ================= K6: link (p_j = PREV precedence) =================
__global__ void k_link(
    const float* __restrict__ pl, const float* __restrict__ pp,
    const float* __restrict__ wsb, float* __restrict__ out)
{
    size_t e = ((size_t)blockIdx.x * 256 + threadIdx.x) * 4;
    int b = (int)(e >> 20);
    int i = (int)((e >> 10) & 1023);
    int j = (int)(e & 1023);
    float wi = wsb[O_WWGT + b * NM + i];
    float4 plv = *(const float4*)(pl + e);
    float4 wj = *(const float4*)(wsb + O_WWGT + b * NM + j);
    float4 pj = *(const float4*)(pp + b * NM + j);
    float4 o;
    o.x = (1.f - wi - wj.x) * plv.x + wi * pj.x; if (i == j)     o.x = 0.f;
    o.y = (1.f - wi - wj.y) * plv.y + wi * pj.y; if (i == j + 1) o.y = 0.f;
    o.z = (1.f - wi - wj.z) * plv.z + wi * pj.z; if (i == j + 2) o.z = 0.f;
    o.w = (1.f - wi - wj.w) * plv.w + wi * pj.w; if (i == j + 3) o.w = 0.f;
    *(float4*)(out + OO_LINK + e) = o;
}

// ================= K6b: fwd[b,r,i] = sum_j prw[b,r,j]*link[b,i,j] =================
__global__ void k_fwd(const float* __restrict__ lnkout, const float* __restrict__ prw,
                      float* __restrict__ wsb)
{
    int gid = blockIdx.x * 256 + threadIdx.x;   // B*M
    int b = gid >> 10, i = gid & 1023;
    const float* row = lnkout + OO_LINK + (size_t)gid * NM;
    const float* rw = prw + b * (NR * NM);
    float a0 = 0, a1 = 0, a2 = 0, a3 = 0;
    for (int j = 0; j < NM; j++) {
        float l = row[j];
        a0 += l * rw[j]; a1 += l * rw[1024 + j]; a2 += l * rw[2048 + j]; a3 += l * rw[3072 + j];
    }
    wsb[O_FWD + (size_t)(b * 4 + 0) * NM + i] = a0;
    wsb[O_FWD + (size_t)(b * 4 + 1) * NM + i] = a1;
    wsb[O_FWD + (size_t)(b * 4 + 2) * NM + i] = a2;
    wsb[O_FWD + (size_t)(b * 4 + 3) * NM + i] = a3;
}

// ================= K6c: bwd[b,r,i] = sum_j prw[b,r,j]*link[b,j,i] =================
__global__ void k_bwd(const float* __restrict__ lnkout, const float* __restrict__ prw,
                      float* __restrict__ wsb)
{
    int gid = blockIdx.x * 256 + threadIdx.x;   // B*M
    int b = gid >> 10, col = gid & 1023;
    const float* rw = prw + b * (NR * NM);
    float a0 = 0, a1 = 0, a2 = 0, a3 = 0;
    const float* base = lnkout + OO_LINK + (size_t)b * NM * NM + col;
    for (int j = 0; j < NM; j++) {
        float l = base[(size_t)j * NM];
        a0 += rw[j] * l; a1 += rw[1024 + j] * l; a2 += rw[2048 + j] * l; a3 += rw[3072 + j] * l;
    }
    wsb[O_BWD + (size_t)(b * 4 + 0) * NM + col] = a0;
    wsb[O_BWD + (size_t)(b * 4 + 1) * NM + col] = a1;
    wsb[O_BWD + (size_t)(b * 4 + 2) * NM + col] = a2;
    wsb[O_BWD + (size_t)(b * 4 + 3) * NM + col] = a3;
}

// ================= K7a: read cosine sims vs NEW memory (f32 from out) =================
__global__ void k_rsim(const float* __restrict__ outmem, float* __restrict__ wsb)
{
    int idx = blockIdx.x * 256 + threadIdx.x;   // B*R*M
    int b = idx >> 12, r = (idx >> 10) & 3, m = idx & 1023;
    const float* rk = wsb + O_RK + (b * 4 + r) * 64;
    const float* row = outmem + OO_MEM + (size_t)(b * NM + m) * 64;
    float kn2 = 0.f, dot = 0.f;
    for (int w = 0; w < 64; w++) {
        float kv = rk[w];
        kn2 += kv * kv;
        dot += kv * row[w];
    }
    float sim = dot / (sqrtf(kn2 + EPSF) * wsb[O_MN + b * NM + m]);
    wsb[O_RSIM + idx] = sim * wsb[O_RSTR + b * 4 + r];
}

// ================= K7b: read softmax + combine modes =================
__global__ void k_rfin(float* __restrict__ wsb, float* __restrict__ out)
{
    int i = blockIdx.x * 64 + threadIdx.x;
    if (i >= NB * NR) return;
    int b = i >> 2, r = i & 3;
    const float* sim = wsb + O_RSIM + (size_t)i * NM;
    float mx = -1e30f;
    for (int m = 0; m < NM; m++) mx = fmaxf(mx, sim[m]);
    float se = 0.f;
    for (int m = 0; m < NM; m++) se += expf(sim[m] - mx);
    float inv = 1.f / se;
    float bm = wsb[O_RM + b * 12 + r * 3 + 0];
    float fm = wsb[O_RM + b * 12 + r * 3 + 1];
    float cm = wsb[O_RM + b * 12 + r * 3 + 2];
    for (int m = 0; m < NM; m++) {
        float p = expf(sim[m] - mx) * inv;
        size_t o = (size_t)i * NM + m;
        float v = cm * p + fm * wsb[O_FWD + o] + bm * wsb[O_BWD + o];
        wsb[O_RWTS + o] = v;
        out[OO_RW + o] = v;
    }
}

// ================= K8: read_words =================
__global__ __launch_bounds__(64) void k_rwords(
    const float* __restrict__ wsb, float* __restrict__ out)
{
    int br = blockIdx.x; int b = br >> 2; int w = threadIdx.x;
    const float* rwt = wsb + O_RWTS + (size_t)br * NM;
    const float* mem = out + OO_MEM + (size_t)b * NM * 64;
    float acc = 0.f;
    for (int m = 0; m < NM; m++) acc += rwt[m] * mem[(size_t)m * 64 + w];
    out[OO_RWORDS + br * 64 + w] = acc;
}

extern "C" void kernel_launch(void* const* d_in, const int* in_sizes, int n_in,
                              void* d_out, int out_size, void* d_ws, size_t ws_size,
                              hipStream_t stream) {
    const float* wv_w = (const float*)d_in[0];  const float* wv_b = (const float*)d_in[1];
    const float* ev_w = (const float*)d_in[2];  const float* ev_b = (const float*)d_in[3];
    const float* fg_w = (const float*)d_in[4];  const float* fg_b = (const float*)d_in[5];
    const float* ag_w = (const float*)d_in[6];  const float* ag_b = (const float*)d_in[7];
    const float* wg_w = (const float*)d_in[8];  const float* wg_b = (const float*)d_in[9];
    const float* rm_w = (const float*)d_in[10]; const float* rm_b = (const float*)d_in[11];
    const float* ws_w = (const float*)d_in[12]; const float* ws_b = (const float*)d_in[13];
    const float* rs_w = (const float*)d_in[14]; const float* rs_b = (const float*)d_in[15];
    const float* wk_w = (const float*)d_in[16]; const float* wk_b = (const float*)d_in[17];
    const float* rk_w = (const float*)d_in[18]; const float* rk_b = (const float*)d_in[19];
    const float* x   = (const float*)d_in[20];
    const float* pm  = (const float*)d_in[21];
    const float* prw = (const float*)d_in[22];
    const float* pww = (const float*)d_in[23];
    const float* pl  = (const float*)d_in[24];
    const float* pp  = (const float*)d_in[25];
    const float* pu  = (const float*)d_in[26];
    float* out = (float*)d_out;
    float* wsb = (float*)d_ws;

    k_controller<<<NB, 512, 0, stream>>>(x, wv_w, wv_b, ev_w, ev_b, fg_w, fg_b, ag_w, ag_b,
                                         wg_w, wg_b, rm_w, rm_b, ws_w, ws_b, rs_w, rs_b,
                                         wk_w, wk_b, rk_w, rk_b, wsb);
    k_rmsm<<<4, 64, 0, stream>>>(wsb);
    k_usage<<<(NB * NM) / 256, 256, 0, stream>>>(pu, prw, pww, wsb, out);
    k_alloc<<<NB, 1024, 0, stream>>>(wsb);
    k_wsim<<<(NB * NM) / 256, 256, 0, stream>>>(pm, wsb);
    k_wfin<<<1, 64, 0, stream>>>(pp, wsb, out);
    k_mem<<<(NB * NM) / 256, 256, 0, stream>>>(pm, wsb, out);
    k_link<<<(NB * NM * (NM / 4)) / 256, 256, 0, stream>>>(pl, pp, wsb, out);
    k_fwd<<<(NB * NM) / 256, 256, 0, stream>>>(out, prw, wsb);
    k_bwd<<<(NB * NM) / 256, 256, 0, stream>>>(out, prw, wsb);
    k_rsim<<<(NB * NR * NM) / 256, 256, 0, stream>>>(out, wsb);
    k_rfin<<<4, 64, 0, stream>>>(wsb, out);
    k_rwords<<<NB * NR, 64, 0, stream>>>(wsb, out);
}

// Round 6
// 391.628 us; speedup vs baseline: 2.5651x; 2.5651x over previous
//
#include <hip/hip_runtime.h>

#define NB 64       // batch
#define ND 512      // input dim
#define NM 1024     // memory slots
#define NR 4        // read heads
#define EPSF 1e-6f

// ---- workspace float offsets ----
static const size_t O_WV    = 0;         // B*64
static const size_t O_EV    = 4096;      // B*64
static const size_t O_FG    = 8192;      // B*4
static const size_t O_AG    = 8448;      // B
static const size_t O_WG    = 8512;      // B
static const size_t O_RMRAW = 8576;      // B*12 raw
static const size_t O_RM    = 9344;      // B*12 softmaxed
static const size_t O_WK    = 10112;     // B*64
static const size_t O_WSTR  = 14208;     // B
static const size_t O_RK    = 14272;     // B*256
static const size_t O_RSTR  = 30656;     // B*4
static const size_t O_USAGE = 30912;     // B*M
static const size_t O_WAW   = 96448;     // B*M
static const size_t O_WWGT  = 161984;    // B*M
static const size_t O_PREC  = 227520;    // B*M
static const size_t O_MN    = 293056;    // B*M
static const size_t O_FWD   = 358592;    // B*R*M
static const size_t O_BWD   = 620736;    // B*R*M
static const size_t O_RWTS  = 882880;    // B*R*M

// ---- output element offsets (FLOAT32 elements) ----
static const size_t OO_RWORDS = 0;          // B*R*W   = 16384
static const size_t OO_MEM    = 16384;      // B*M*W   = 4194304
static const size_t OO_RW     = 4210688;    // B*R*M   = 262144
static const size_t OO_WWGT   = 4472832;    // B*1*M   = 65536
static const size_t OO_LINK   = 4538368;    // B*1*M*M = 67108864
static const size_t OO_PREC   = 71647232;   // B*1*M   = 65536
static const size_t OO_USAGE  = 71712768;   // B*M     = 65536

__device__ __forceinline__ float sigm(float x) { return 1.f / (1.f + expf(-x)); }
__device__ __forceinline__ float softplus_(float x) { return fmaxf(x, 0.f) + log1pf(expf(-fabsf(x))); }

// ================= K1: controller linears, one thread per (b, col) =================
__global__ void k_controller(
    const float* __restrict__ x,
    const float* __restrict__ wv_w, const float* __restrict__ wv_b,
    const float* __restrict__ ev_w, const float* __restrict__ ev_b,
    const float* __restrict__ fg_w, const float* __restrict__ fg_b,
    const float* __restrict__ ag_w, const float* __restrict__ ag_b,
    const float* __restrict__ wg_w, const float* __restrict__ wg_b,
    const float* __restrict__ rm_w, const float* __restrict__ rm_b,
    const float* __restrict__ ws_w, const float* __restrict__ ws_b,
    const float* __restrict__ rs_w, const float* __restrict__ rs_b,
    const float* __restrict__ wk_w, const float* __restrict__ wk_b,
    const float* __restrict__ rk_w, const float* __restrict__ rk_b,
    float* __restrict__ wsb)
{
    int b = blockIdx.x;
    int c = threadIdx.x;
    if (c >= 471) return;
    const float* wp; const float* bp; int O; int cl; int act; size_t dsto;
    if (c < 64)       { wp = wv_w; bp = wv_b; O = 64;  cl = c;       act = 0; dsto = O_WV + b * 64 + cl; }
    else if (c < 128) { wp = ev_w; bp = ev_b; O = 64;  cl = c - 64;  act = 1; dsto = O_EV + b * 64 + cl; }
    else if (c < 132) { wp = fg_w; bp = fg_b; O = 4;   cl = c - 128; act = 1; dsto = O_FG + b * 4 + cl; }
    else if (c < 133) { wp = ag_w; bp = ag_b; O = 1;   cl = 0;       act = 1; dsto = O_AG + b; }
    else if (c < 134) { wp = wg_w; bp = wg_b; O = 1;   cl = 0;       act = 1; dsto = O_WG + b; }
    else if (c < 146) { wp = rm_w; bp = rm_b; O = 12;  cl = c - 134; act = 0; dsto = O_RMRAW + b * 12 + cl; }
    else if (c < 147) { wp = ws_w; bp = ws_b; O = 1;   cl = 0;       act = 2; dsto = O_WSTR + b; }
    else if (c < 151) { wp = rs_w; bp = rs_b; O = 4;   cl = c - 147; act = 2; dsto = O_RSTR + b * 4 + cl; }
    else if (c < 215) { wp = wk_w; bp = wk_b; O = 64;  cl = c - 151; act = 0; dsto = O_WK + b * 64 + cl; }
    else              { wp = rk_w; bp = rk_b; O = 256; cl = c - 215; act = 0; dsto = O_RK + b * 256 + cl; }
    float acc = bp[cl];
    const float* xb = x + b * ND;
    for (int d = 0; d < ND; ++d) acc += xb[d] * wp[d * O + cl];
    if (act == 1) acc = sigm(acc);
    else if (act == 2) acc = softplus_(acc);
    wsb[dsto] = acc;
}

// ================= K1b: read-mode softmax =================
__global__ void k_rmsm(float* __restrict__ wsb)
{
    int i = blockIdx.x * 64 + threadIdx.x;
    if (i >= NB * NR) return;
    int b = i >> 2, r = i & 3;
    const float* raw = wsb + O_RMRAW + b * 12 + r * 3;
    float a0 = raw[0], a1 = raw[1], a2 = raw[2];
    float mx = fmaxf(a0, fmaxf(a1, a2));
    float e0 = expf(a0 - mx), e1 = expf(a1 - mx), e2 = expf(a2 - mx);
    float s = e0 + e1 + e2;
    float* dst = wsb + O_RM + b * 12 + r * 3;
    dst[0] = e0 / s; dst[1] = e1 / s; dst[2] = e2 / s;
}

// ================= K2: usage =================
__global__ void k_usage(
    const float* __restrict__ pu, const float* __restrict__ prw,
    const float* __restrict__ pww, float* __restrict__ wsb, float* __restrict__ out)
{
    int idx = blockIdx.x * 256 + threadIdx.x;
    int b = idx >> 10, m = idx & 1023;
    float u0 = pu[idx];
    float uaw = u0 + (1.f - u0) * pww[idx];
    float phi = 1.f;
#pragma unroll
    for (int r = 0; r < NR; r++)
        phi *= (1.f - wsb[O_FG + b * 4 + r] * prw[(b * 4 + r) * NM + m]);
    float u = uaw * phi;
    wsb[O_USAGE + idx] = u;
    out[OO_USAGE + idx] = u;
}

// ================= K3: allocation (bitonic sort + Hillis-Steele product scan) =================
__global__ __launch_bounds__(1024) void k_alloc(float* __restrict__ wsb)
{
    __shared__ float sv[1024];
    __shared__ int   si[1024];
    __shared__ float sp[1024];
    int b = blockIdx.x, t = threadIdx.x;
    sv[t] = EPSF + (1.0f - EPSF) * wsb[O_USAGE + b * NM + t];
    si[t] = t;
    __syncthreads();
    for (int k = 2; k <= 1024; k <<= 1) {
        for (int j = k >> 1; j > 0; j >>= 1) {
            int ixj = t ^ j;
            if (ixj > t) {
                float a = sv[t], c = sv[ixj];
                int ia = si[t], ic = si[ixj];
                bool asc = (t & k) == 0;
                bool gt = (a > c) || (a == c && ia > ic);
                if (gt == asc) { sv[t] = c; sv[ixj] = a; si[t] = ic; si[ixj] = ia; }
            }
            __syncthreads();
        }
    }
    sp[t] = sv[t];
    __syncthreads();
    for (int off = 1; off < 1024; off <<= 1) {
        float v = sp[t];
        float o = (t >= off) ? sp[t - off] : 1.f;
        __syncthreads();
        sp[t] = v * o;
        __syncthreads();
    }
    float excl = (t == 0) ? 1.f : sp[t - 1];
    wsb[O_WAW + b * NM + si[t]] = (1.f - sv[t]) * excl;
}

// ================= K4: fused write cosine + softmax + write_weights + precedence =================
__global__ __launch_bounds__(256) void k_writew(
    const float* __restrict__ pm, const float* __restrict__ pp,
    float* __restrict__ wsb, float* __restrict__ out)
{
    int b = blockIdx.x, t = threadIdx.x;
    __shared__ float red[256];
    const float* wk = wsb + O_WK + b * 64;
    float kn2 = 0.f;
#pragma unroll
    for (int w = 0; w < 64; w++) { float v = wk[w]; kn2 += v * v; }
    float kn = sqrtf(kn2 + EPSF);
    float wstr = wsb[O_WSTR + b];
    float sim[4];
#pragma unroll
    for (int k = 0; k < 4; k++) {
        int m = t + k * 256;
        const float* row = pm + ((size_t)(b * NM + m)) * 64;
        float dot = 0.f, mn2 = 0.f;
        for (int w = 0; w < 64; w++) { float pv = row[w]; dot += wk[w] * pv; mn2 += pv * pv; }
        sim[k] = dot / (kn * sqrtf(mn2 + EPSF)) * wstr;
    }
    float lm = fmaxf(fmaxf(sim[0], sim[1]), fmaxf(sim[2], sim[3]));
    red[t] = lm; __syncthreads();
    for (int s = 128; s > 0; s >>= 1) { if (t < s) red[t] = fmaxf(red[t], red[t + s]); __syncthreads(); }
    float mx = red[0]; __syncthreads();
    float e[4]; float ls = 0.f;
#pragma unroll
    for (int k = 0; k < 4; k++) { e[k] = expf(sim[k] - mx); ls += e[k]; }
    red[t] = ls; __syncthreads();
    for (int s = 128; s > 0; s >>= 1) { if (t < s) red[t] += red[t + s]; __syncthreads(); }
    float inv = 1.f / red[0]; __syncthreads();
    float ag = wsb[O_AG + b], wg = wsb[O_WG + b];
    float wwv[4]; float lsum = 0.f;
#pragma unroll
    for (int k = 0; k < 4; k++) {
        int m = t + k * 256;
        float wcw = e[k] * inv;
        float waw = wsb[O_WAW + b * NM + m];
        float w_ = wg * (ag * waw + (1.f - ag) * wcw);
        wwv[k] = w_; lsum += w_;
        wsb[O_WWGT + b * NM + m] = w_;
        out[OO_WWGT + b * NM + m] = w_;
    }
    red[t] = lsum; __syncthreads();
    for (int s = 128; s > 0; s >>= 1) { if (t < s) red[t] += red[t + s]; __syncthreads(); }
    float wwsum = red[0];
#pragma unroll
    for (int k = 0; k < 4; k++) {
        int m = t + k * 256;
        float pr = (1.f - wwsum) * pp[b * NM + m] + wwv[k];
        wsb[O_PREC + b * NM + m] = pr;
        out[OO_PREC + b * NM + m] = pr;
    }
}

// ================= K5: memory update + norms =================
__global__ void k_mem(const float* __restrict__ pm, float* __restrict__ wsb, float* __restrict__ out)
{
    int gid = blockIdx.x * 256 + threadIdx.x;
    int b = gid >> 10;
    float w_ = wsb[O_WWGT + gid];
    const float* evp = wsb + O_EV + b * 64;
    const float* wvp = wsb + O_WV + b * 64;
    const float* pmr = pm + (size_t)gid * 64;
    float* outr = out + OO_MEM + (size_t)gid * 64;
    float s = 0.f;
    for (int w = 0; w < 64; w++) {
        float val = pmr[w] * (1.f - w_ * evp[w]) + w_ * wvp[w];
        outr[w] = val;
        s += val * val;
    }
    wsb[O_MN + gid] = sqrtf(s + EPSF);
}

// ================= K6: link + fused fwd (block per (b,i) row) =================
__global__ __launch_bounds__(256) void k_linkfwd(
    const float* __restrict__ pl, const float* __restrict__ pp,
    const float* __restrict__ prw, float* __restrict__ wsb, float* __restrict__ out)
{
    int gid = blockIdx.x;            // b*NM + i
    int b = gid >> 10, i = gid & 1023;
    int t = threadIdx.x;
    int j0 = t * 4;
    size_t rowbase = (size_t)gid * NM;
    float wi = wsb[O_WWGT + gid];
    float4 plv = *(const float4*)(pl + rowbase + j0);
    float4 wj  = *(const float4*)(wsb + O_WWGT + b * NM + j0);
    float4 pj  = *(const float4*)(pp + b * NM + j0);
    float4 o;
    o.x = (1.f - wi - wj.x) * plv.x + wi * pj.x; if (i == j0)     o.x = 0.f;
    o.y = (1.f - wi - wj.y) * plv.y + wi * pj.y; if (i == j0 + 1) o.y = 0.f;
    o.z = (1.f - wi - wj.z) * plv.z + wi * pj.z; if (i == j0 + 2) o.z = 0.f;
    o.w = (1.f - wi - wj.w) * plv.w + wi * pj.w; if (i == j0 + 3) o.w = 0.f;
    *(float4*)(out + OO_LINK + rowbase + j0) = o;
    // fwd accumulation: a[r] = sum_j rw[r][j] * link[i][j]
    const float* rwb = prw + b * (NR * NM);
    float4 r0 = *(const float4*)(rwb + j0);
    float4 r1 = *(const float4*)(rwb + 1024 + j0);
    float4 r2 = *(const float4*)(rwb + 2048 + j0);
    float4 r3 = *(const float4*)(rwb + 3072 + j0);
    float a0 = o.x * r0.x + o.y * r0.y + o.z * r0.z + o.w * r0.w;
    float a1 = o.x * r1.x + o.y * r1.y + o.z * r1.z + o.w * r1.w;
    float a2 = o.x * r2.x + o.y * r2.y + o.z * r2.z + o.w * r2.w;
    float a3 = o.x * r3.x + o.y * r3.y + o.z * r3.z + o.w * r3.w;
#pragma unroll
    for (int off = 32; off > 0; off >>= 1) {
        a0 += __shfl_down(a0, off); a1 += __shfl_down(a1, off);
        a2 += __shfl_down(a2, off); a3 += __shfl_down(a3, off);
    }
    __shared__ float red[4][4];
    int wv = t >> 6, ln = t & 63;
    if (ln == 0) { red[wv][0] = a0; red[wv][1] = a1; red[wv][2] = a2; red[wv][3] = a3; }
    __syncthreads();
    if (t < 4) {
        float s = red[0][t] + red[1][t] + red[2][t] + red[3][t];
        wsb[O_FWD + (size_t)(b * 4 + t) * NM + i] = s;
    }
}

// ================= K6c: bwd[b,r,i] = sum_j prw[b,r,j]*link[b,j,i] =================
__global__ void k_bwd(const float* __restrict__ lnkout, const float* __restrict__ prw,
                      float* __restrict__ wsb)
{
    int gid = blockIdx.x * 256 + threadIdx.x;   // B*M
    int b = gid >> 10, col = gid & 1023;
    const float* rw = prw + b * (NR * NM);
    float a0 = 0, a1 = 0, a2 = 0, a3 = 0;
    const float* base = lnkout + OO_LINK + (size_t)b * NM * NM + col;
    for (int j = 0; j < NM; j++) {
        float l = base[(size_t)j * NM];
        a0 += rw[j] * l; a1 += rw[1024 + j] * l; a2 += rw[2048 + j] * l; a3 += rw[3072 + j] * l;
    }
    wsb[O_BWD + (size_t)(b * 4 + 0) * NM + col] = a0;
    wsb[O_BWD + (size_t)(b * 4 + 1) * NM + col] = a1;
    wsb[O_BWD + (size_t)(b * 4 + 2) * NM + col] = a2;
    wsb[O_BWD + (size_t)(b * 4 + 3) * NM + col] = a3;
}

// ================= K7: fused read cosine + softmax + combine (block per (b,r)) =================
__global__ __launch_bounds__(256) void k_readw(
    float* __restrict__ wsb, float* __restrict__ out)
{
    int b = blockIdx.x >> 2, r = blockIdx.x & 3, t = threadIdx.x;
    __shared__ float red[256];
    const float* rk = wsb + O_RK + (b * 4 + r) * 64;
    float kn2 = 0.f;
#pragma unroll
    for (int w = 0; w < 64; w++) { float v = rk[w]; kn2 += v * v; }
    float kn = sqrtf(kn2 + EPSF);
    float rstr = wsb[O_RSTR + b * 4 + r];
    float sim[4];
#pragma unroll
    for (int k = 0; k < 4; k++) {
        int m = t + k * 256;
        const float* row = out + OO_MEM + ((size_t)(b * NM + m)) * 64;
        float dot = 0.f;
        for (int w = 0; w < 64; w++) dot += rk[w] * row[w];
        sim[k] = dot / (kn * wsb[O_MN + b * NM + m]) * rstr;
    }
    float lm = fmaxf(fmaxf(sim[0], sim[1]), fmaxf(sim[2], sim[3]));
    red[t] = lm; __syncthreads();
    for (int s = 128; s > 0; s >>= 1) { if (t < s) red[t] = fmaxf(red[t], red[t + s]); __syncthreads(); }
    float mx = red[0]; __syncthreads();
    float e[4]; float ls = 0.f;
#pragma unroll
    for (int k = 0; k < 4; k++) { e[k] = expf(sim[k] - mx); ls += e[k]; }
    red[t] = ls; __syncthreads();
    for (int s = 128; s > 0; s >>= 1) { if (t < s) red[t] += red[t + s]; __syncthreads(); }
    float inv = 1.f / red[0];
    float bm = wsb[O_RM + b * 12 + r * 3 + 0];
    float fm = wsb[O_RM + b * 12 + r * 3 + 1];
    float cm = wsb[O_RM + b * 12 + r * 3 + 2];
#pragma unroll
    for (int k = 0; k < 4; k++) {
        int m = t + k * 256;
        float p = e[k] * inv;
        size_t o = (size_t)(b * 4 + r) * NM + m;
        float v = cm * p + fm * wsb[O_FWD + o] + bm * wsb[O_BWD + o];
        wsb[O_RWTS + o] = v;
        out[OO_RW + o] = v;
    }
}

// ================= K8: read_words =================
__global__ __launch_bounds__(64) void k_rwords(
    const float* __restrict__ wsb, float* __restrict__ out)
{
    int br = blockIdx.x; int b = br >> 2; int w = threadIdx.x;
    const float* rwt = wsb + O_RWTS + (size_t)br * NM;
    const float* mem = out + OO_MEM + (size_t)b * NM * 64;
    float acc = 0.f;
    for (int m = 0; m < NM; m++) acc += rwt[m] * mem[(size_t)m * 64 + w];
    out[OO_RWORDS + br * 64 + w] = acc;
}

extern "C" void kernel_launch(void* const* d_in, const int* in_sizes, int n_in,
                              void* d_out, int out_size, void* d_ws, size_t ws_size,
                              hipStream_t stream) {
    const float* wv_w = (const float*)d_in[0];  const float* wv_b = (const float*)d_in[1];
    const float* ev_w = (const float*)d_in[2];  const float* ev_b = (const float*)d_in[3];
    const float* fg_w = (const float*)d_in[4];  const float* fg_b = (const float*)d_in[5];
    const float* ag_w = (const float*)d_in[6];  const float* ag_b = (const float*)d_in[7];
    const float* wg_w = (const float*)d_in[8];  const float* wg_b = (const float*)d_in[9];
    const float* rm_w = (const float*)d_in[10]; const float* rm_b = (const float*)d_in[11];
    const float* ws_w = (const float*)d_in[12]; const float* ws_b = (const float*)d_in[13];
    const float* rs_w = (const float*)d_in[14]; const float* rs_b = (const float*)d_in[15];
    const float* wk_w = (const float*)d_in[16]; const float* wk_b = (const float*)d_in[17];
    const float* rk_w = (const float*)d_in[18]; const float* rk_b = (const float*)d_in[19];
    const float* x   = (const float*)d_in[20];
    const float* pm  = (const float*)d_in[21];
    const float* prw = (const float*)d_in[22];
    const float* pww = (const float*)d_in[23];
    const float* pl  = (const float*)d_in[24];
    const float* pp  = (const float*)d_in[25];
    const float* pu  = (const float*)d_in[26];
    float* out = (float*)d_out;
    float* wsb = (float*)d_ws;

    k_controller<<<NB, 512, 0, stream>>>(x, wv_w, wv_b, ev_w, ev_b, fg_w, fg_b, ag_w, ag_b,
                                         wg_w, wg_b, rm_w, rm_b, ws_w, ws_b, rs_w, rs_b,
                                         wk_w, wk_b, rk_w, rk_b, wsb);
    k_rmsm<<<4, 64, 0, stream>>>(wsb);
    k_usage<<<(NB * NM) / 256, 256, 0, stream>>>(pu, prw, pww, wsb, out);
    k_alloc<<<NB, 1024, 0, stream>>>(wsb);
    k_writew<<<NB, 256, 0, stream>>>(pm, pp, wsb, out);
    k_mem<<<(NB * NM) / 256, 256, 0, stream>>>(pm, wsb, out);
    k_linkfwd<<<NB * NM, 256, 0, stream>>>(pl, pp, prw, wsb, out);
    k_bwd<<<(NB * NM) / 256, 256, 0, stream>>>(out, prw, wsb);
    k_readw<<<NB * NR, 256, 0, stream>>>(wsb, out);
    k_rwords<<<NB * NR, 64, 0, stream>>>(wsb, out);
}